// Round 2
// baseline (429.501 us; speedup 1.0000x reference)
//
#include <hip/hip_runtime.h>

#define NT 256            // 1 output column per thread
#define RROWS 45          // output rows per block (multiple of 9!)
#define STRIP 256         // output cols per block
#define PW 264            // staged (x,y) pairs per row: STRIP + 8 halo
#define NLD 132           // loader threads: PW/2 float4 chunks
#define WID 1024
#define HEI 1024
#define OWD 1016          // valid conv output dim (1024 - 8)

typedef float v2f __attribute__((ext_vector_type(2)));

static __device__ __forceinline__ v2f pkfma(v2f a, v2f b, v2f c) {
#if __has_builtin(__builtin_elementwise_fma)
    return __builtin_elementwise_fma(a, b, c);   // -> v_pk_fma_f32
#else
    v2f r; r.x = fmaf(a.x, b.x, c.x); r.y = fmaf(a.y, b.y, c.y); return r;
#endif
}

__global__ __launch_bounds__(NT, 4)
void ssim_main(const float* __restrict__ X, const float* __restrict__ Y,
               const float* __restrict__ Wg, double* __restrict__ acc)
{
    __shared__ float4 P4[2][PW / 2];   // P4[s][i] = (x_{2i}, y_{2i}, x_{2i+1}, y_{2i+1})
    __shared__ float  wsum[4][2];

    const int t  = threadIdx.x;
    const int r0 = blockIdx.x * RROWS;          // multiple of 9
    const int c0 = blockIdx.y * STRIP;
    const size_t ibase = (size_t)blockIdx.z * (size_t)(WID * HEI);

    // loader role: threads 0..131 stage one float4 (2 cols of x,y) per row
    const bool ldv   = (t < NLD) && (c0 + 2 * t < WID);
    const bool owned = (t < 128);               // halo chunks 128..131 not owned

    // 1D gaussian from row 4 of w2d: w2d[4][k] = g4*g[k], row sum = g4
    float g[9];
    {
        float s = 0.f;
#pragma unroll
        for (int k = 0; k < 9; ++k) { g[k] = Wg[36 + k]; s += g[k]; }
        float rs = __builtin_amdgcn_rcpf(s);
#pragma unroll
        for (int k = 0; k < 9; ++k) g[k] *= rs;
    }

    const float C1 = 0.0004f, C2 = 0.0036f;
    float ssim_acc = 0.f, l1_acc = 0.f;

    // register ring: horizontal-conv results for 9 rows x 5 channels (45 VGPRs)
    v2f  r01[9], r23[9];   // (ux_h, uy_h), (uxx_h, uyy_h)
    float r4[9];           // uxy_h

    const float2* __restrict__ Xp = (const float2*)(X + ibase + c0);
    const float2* __restrict__ Yp = (const float2*)(Y + ibase + c0);

    float2 cx, cy;   // prefetched (2 x-cols), (2 y-cols) for loader threads

    auto preload = [&](int row) {
        if (ldv && row < HEI) {
            cx = Xp[(size_t)row * (WID / 2) + t];
            cy = Yp[(size_t)row * (WID / 2) + t];
        }
    };
    auto store_cur = [&](int row, int slot, bool own_row) {
        if (ldv && row < HEI) {
            P4[slot][t] = make_float4(cx.x, cy.x, cx.y, cy.y);
            if (owned && own_row) l1_acc += fabsf(cx.x - cy.x) + fabsf(cx.y - cy.y);
        }
    };

    // horizontal 9-tap conv of 5 channels for this thread's column (col = c0+t)
    auto hcomp = [&](int slot, v2f& h01, v2f& h23, float& h4) {
        const float2* src = (const float2*)&P4[slot][0];   // src[j] = (x_j, y_j)
        v2f a[9];
#pragma unroll
        for (int k = 0; k < 9; ++k) { float2 p = src[t + k]; a[k] = (v2f){p.x, p.y}; }
        h01 = (v2f)0.f; h23 = (v2f)0.f; h4 = 0.f;
#pragma unroll
        for (int k = 0; k < 9; ++k) {
            v2f gk2 = { g[k], g[k] };
            h01 = pkfma(gk2, a[k], h01);
            h23 = pkfma(gk2, a[k] * a[k], h23);
            h4  = fmaf(g[k], a[k].x * a[k].y, h4);
        }
    };

    // ---- prologue: rows r0..r0+7 -> ring slots 0..7
#pragma unroll
    for (int i = 0; i < 8; ++i) {
        preload(r0 + i);
        store_cur(r0 + i, i & 1, true);
        __syncthreads();
        hcomp(i & 1, r01[i], r23[i], r4[i]);
    }
    preload(r0 + 8);

    const bool vA = (c0 + t < OWD);

#pragma unroll 1
    for (int jb = 0; jb < RROWS / 9; ++jb) {
#pragma unroll
        for (int ju = 0; ju < 9; ++ju) {
            const int j = jb * 9 + ju;
            const int rnew = r0 + j + 8;
            store_cur(rnew, (j + 8) & 1, (j + 8) < RROWS);   // stage row j+8
            __syncthreads();
            if (j < RROWS - 1) preload(rnew + 1);            // prefetch next row
            if (r0 + j < OWD) {                              // block-uniform guard
                const int wnew = (ju + 8) % 9;
                hcomp((j + 8) & 1, r01[wnew], r23[wnew], r4[wnew]);
                v2f u01 = (v2f)0.f, u23 = (v2f)0.f; float u4 = 0.f;
#pragma unroll
                for (int k = 0; k < 9; ++k) {
                    const int s = (ju + k) % 9;              // static after unroll
                    v2f gk2 = { g[k], g[k] };
                    u01 = pkfma(gk2, r01[s], u01);
                    u23 = pkfma(gk2, r23[s], u23);
                    u4  = fmaf(g[k], r4[s], u4);
                }
                float ux = u01.x, uy = u01.y, uxx = u23.x, uyy = u23.y, uxy = u4;
                float uxux = ux * ux, uyuy = uy * uy, uxuy = ux * uy;
                float A1 = 2.f * uxuy + C1;
                float A2 = 2.f * (uxy - uxuy) + C2;
                float B1 = uxux + uyuy + C1;
                float B2 = (uxx - uxux) + (uyy - uyuy) + C2;
                float S  = (A1 * A2) * __builtin_amdgcn_rcpf(B1 * B2);
                ssim_acc += vA ? S : 0.f;
            }
        }
    }

    // ---- reduction: wave shfl -> LDS -> one double atomic pair per block
#pragma unroll
    for (int off = 32; off > 0; off >>= 1) {
        ssim_acc += __shfl_down(ssim_acc, off);
        l1_acc   += __shfl_down(l1_acc, off);
    }
    const int wid = t >> 6;
    if ((t & 63) == 0) { wsum[wid][0] = ssim_acc; wsum[wid][1] = l1_acc; }
    __syncthreads();
    if (t == 0) {
        double s = 0.0, l = 0.0;
#pragma unroll
        for (int w = 0; w < 4; ++w) { s += (double)wsum[w][0]; l += (double)wsum[w][1]; }
        atomicAdd(acc + 0, s);
        atomicAdd(acc + 1, l);
    }
}

__global__ void ssim_final(const double* __restrict__ acc, float* __restrict__ out)
{
    const double n_ssim = 33032192.0;   // 32*1016*1016
    const double n_l1   = 33554432.0;   // 32*1024*1024
    double ssim_loss = 1.0 - acc[0] / n_ssim;
    double l1        = acc[1] / n_l1;
    out[0] = (float)(0.5 * ssim_loss + 1.0 * l1);
}

extern "C" void kernel_launch(void* const* d_in, const int* in_sizes, int n_in,
                              void* d_out, int out_size, void* d_ws, size_t ws_size,
                              hipStream_t stream)
{
    const float* X  = (const float*)d_in[0];
    const float* Y  = (const float*)d_in[1];
    const float* Wg = (const float*)d_in[2];
    float*  out = (float*)d_out;
    double* acc = (double*)d_ws;

    hipMemsetAsync(acc, 0, 2 * sizeof(double), stream);
    dim3 grid(23, 4, 32);   // rowblocks(ceil(1016/45)) x col-strips x images
    ssim_main<<<grid, NT, 0, stream>>>(X, Y, Wg, acc);
    ssim_final<<<1, 1, 0, stream>>>(acc, out);
}

// Round 3
// 423.016 us; speedup vs baseline: 1.0153x; 1.0153x over previous
//
#include <hip/hip_runtime.h>

#define NT 256            // 1 output column per thread
#define RROWS 45          // output rows per block (multiple of 9!)
#define STRIP 256         // output cols per block
#define PW 264            // staged (x,y) pairs per row: STRIP + 8 halo
#define NLD 132           // loader threads: PW/2 float4 chunks
#define WID 1024
#define HEI 1024
#define OWD 1016          // valid conv output dim (1024 - 8)

typedef float v2f __attribute__((ext_vector_type(2)));

// compile-time for: indices are literal constants in the AST -> SROA-proof
template<int I> struct IC { static constexpr int v = I; };
template<int N, int I = 0, typename F>
__device__ __forceinline__ void sfor(F&& f) {
    if constexpr (I < N) { f(IC<I>{}); sfor<N, I + 1>(f); }
}

static __device__ __forceinline__ v2f pkfma(v2f a, v2f b, v2f c) {
#if __has_builtin(__builtin_elementwise_fma)
    return __builtin_elementwise_fma(a, b, c);   // -> v_pk_fma_f32
#else
    v2f r; r.x = fmaf(a.x, b.x, c.x); r.y = fmaf(a.y, b.y, c.y); return r;
#endif
}

__global__ __launch_bounds__(NT, 2)
void ssim_main(const float* __restrict__ X, const float* __restrict__ Y,
               const float* __restrict__ Wg, double* __restrict__ acc)
{
    __shared__ float4 P4[2][PW / 2];   // P4[s][i] = (x_{2i}, y_{2i}, x_{2i+1}, y_{2i+1})
    __shared__ float  wsum[4][2];

    const int t  = threadIdx.x;
    const int r0 = blockIdx.x * RROWS;          // multiple of 9
    const int c0 = blockIdx.y * STRIP;
    const size_t ibase = (size_t)blockIdx.z * (size_t)(WID * HEI);

    // loader role: threads 0..131 stage one float4 (2 cols of x,y) per row
    const bool ldv   = (t < NLD) && (c0 + 2 * t < WID);
    const bool owned = (t < 128);               // halo chunks 128..131 not owned

    // 1D gaussian from row 4 of w2d: w2d[4][k] = g4*g[k], row sum = g4
    float g[9];
    {
        float s = 0.f;
        sfor<9>([&](auto K) { constexpr int k = decltype(K)::v;
            g[k] = Wg[36 + k]; s += g[k]; });
        float rs = __builtin_amdgcn_rcpf(s);
        sfor<9>([&](auto K) { constexpr int k = decltype(K)::v; g[k] *= rs; });
    }

    const float C1 = 0.0004f, C2 = 0.0036f;
    float ssim_acc = 0.f, l1_acc = 0.f;

    // register ring: horizontal-conv results for 9 rows x 5 channels (45 VGPRs)
    v2f  r01[9], r23[9];   // (ux_h, uy_h), (uxx_h, uyy_h)
    float r4[9];           // uxy_h

    const float2* __restrict__ Xp = (const float2*)(X + ibase + c0);
    const float2* __restrict__ Yp = (const float2*)(Y + ibase + c0);

    float2 cx, cy;   // prefetched pair for loader threads

    auto preload = [&](int row) {
        if (ldv && row < HEI) {
            cx = Xp[(size_t)row * (WID / 2) + t];
            cy = Yp[(size_t)row * (WID / 2) + t];
        }
    };
    auto store_cur = [&](int row, int slot, bool own_row) {
        if (ldv && row < HEI) {
            P4[slot][t] = make_float4(cx.x, cy.x, cx.y, cy.y);
            if (owned && own_row) l1_acc += fabsf(cx.x - cy.x) + fabsf(cx.y - cy.y);
        }
    };

    // horizontal 9-tap conv of 5 channels for this thread's column (col = c0+t)
    auto hcomp = [&](int slot, v2f& h01, v2f& h23, float& h4) {
        const float2* src = (const float2*)&P4[slot][0];   // src[j] = (x_j, y_j)
        v2f a[9];
        sfor<9>([&](auto K) { constexpr int k = decltype(K)::v;
            float2 p = src[t + k]; a[k] = (v2f){p.x, p.y}; });
        v2f s01 = (v2f)0.f, s23 = (v2f)0.f; float s4 = 0.f;
        sfor<9>([&](auto K) { constexpr int k = decltype(K)::v;
            v2f gk2 = { g[k], g[k] };
            s01 = pkfma(gk2, a[k], s01);
            s23 = pkfma(gk2, a[k] * a[k], s23);
            s4  = fmaf(g[k], a[k].x * a[k].y, s4); });
        h01 = s01; h23 = s23; h4 = s4;
    };

    // ---- prologue: rows r0..r0+7 -> ring slots 0..7
    sfor<8>([&](auto I) {
        constexpr int i = decltype(I)::v;
        preload(r0 + i);
        store_cur(r0 + i, i & 1, true);
        __syncthreads();
        hcomp(i & 1, r01[i], r23[i], r4[i]);
    });
    preload(r0 + 8);

    const bool vA = (c0 + t < OWD);

#pragma unroll 1
    for (int jb = 0; jb < RROWS / 9; ++jb) {
        sfor<9>([&](auto JU) {
            constexpr int ju = decltype(JU)::v;
            const int j = jb * 9 + ju;
            const int rnew = r0 + j + 8;
            store_cur(rnew, (j + 8) & 1, (j + 8) < RROWS);   // stage row j+8
            __syncthreads();
            if (j < RROWS - 1) preload(rnew + 1);            // prefetch next row
            if (r0 + j < OWD) {                              // block-uniform guard
                constexpr int wnew = (ju + 8) % 9;
                hcomp((j + 8) & 1, r01[wnew], r23[wnew], r4[wnew]);
                v2f u01 = (v2f)0.f, u23 = (v2f)0.f; float u4 = 0.f;
                sfor<9>([&](auto K) {
                    constexpr int k = decltype(K)::v;
                    constexpr int s = (ju + k) % 9;          // literal constant
                    v2f gk2 = { g[k], g[k] };
                    u01 = pkfma(gk2, r01[s], u01);
                    u23 = pkfma(gk2, r23[s], u23);
                    u4  = fmaf(g[k], r4[s], u4);
                });
                float ux = u01.x, uy = u01.y, uxx = u23.x, uyy = u23.y, uxy = u4;
                float uxux = ux * ux, uyuy = uy * uy, uxuy = ux * uy;
                float A1 = 2.f * uxuy + C1;
                float A2 = 2.f * (uxy - uxuy) + C2;
                float B1 = uxux + uyuy + C1;
                float B2 = (uxx - uxux) + (uyy - uyuy) + C2;
                float S  = (A1 * A2) * __builtin_amdgcn_rcpf(B1 * B2);
                ssim_acc += vA ? S : 0.f;
            }
        });
    }

    // ---- reduction: wave shfl -> LDS -> one double atomic pair per block
#pragma unroll
    for (int off = 32; off > 0; off >>= 1) {
        ssim_acc += __shfl_down(ssim_acc, off);
        l1_acc   += __shfl_down(l1_acc, off);
    }
    const int wid = t >> 6;
    if ((t & 63) == 0) { wsum[wid][0] = ssim_acc; wsum[wid][1] = l1_acc; }
    __syncthreads();
    if (t == 0) {
        double s = 0.0, l = 0.0;
#pragma unroll
        for (int w = 0; w < 4; ++w) { s += (double)wsum[w][0]; l += (double)wsum[w][1]; }
        atomicAdd(acc + 0, s);
        atomicAdd(acc + 1, l);
    }
}

__global__ void ssim_final(const double* __restrict__ acc, float* __restrict__ out)
{
    const double n_ssim = 33032192.0;   // 32*1016*1016
    const double n_l1   = 33554432.0;   // 32*1024*1024
    double ssim_loss = 1.0 - acc[0] / n_ssim;
    double l1        = acc[1] / n_l1;
    out[0] = (float)(0.5 * ssim_loss + 1.0 * l1);
}

extern "C" void kernel_launch(void* const* d_in, const int* in_sizes, int n_in,
                              void* d_out, int out_size, void* d_ws, size_t ws_size,
                              hipStream_t stream)
{
    const float* X  = (const float*)d_in[0];
    const float* Y  = (const float*)d_in[1];
    const float* Wg = (const float*)d_in[2];
    float*  out = (float*)d_out;
    double* acc = (double*)d_ws;

    hipMemsetAsync(acc, 0, 2 * sizeof(double), stream);
    dim3 grid(23, 4, 32);   // rowblocks(ceil(1016/45)) x col-strips x images
    ssim_main<<<grid, NT, 0, stream>>>(X, Y, Wg, acc);
    ssim_final<<<1, 1, 0, stream>>>(acc, out);
}

// Round 4
// 318.595 us; speedup vs baseline: 1.3481x; 1.3278x over previous
//
#include <hip/hip_runtime.h>

#define NT 256            // 1 output column per thread
#define RROWS 45          // output rows per block (multiple of 9!)
#define STRIP 256         // output cols per block
#define PW 264            // staged (x,y) pairs per row: STRIP + 8 halo
#define NLD 132           // loader threads: PW/2 float4 chunks
#define WID 1024
#define HEI 1024
#define OWD 1016          // valid conv output dim (1024 - 8)

typedef float v2f __attribute__((ext_vector_type(2)));

// compile-time for: indices are literal constants in the AST -> SROA-proof
template<int I> struct IC { static constexpr int v = I; };
template<int N, int I = 0, typename F>
__device__ __forceinline__ void sfor(F&& f) {
    if constexpr (I < N) { f(IC<I>{}); sfor<N, I + 1>(f); }
}

static __device__ __forceinline__ v2f pkfma(v2f a, v2f b, v2f c) {
#if __has_builtin(__builtin_elementwise_fma)
    return __builtin_elementwise_fma(a, b, c);   // -> v_pk_fma_f32
#else
    v2f r; r.x = fmaf(a.x, b.x, c.x); r.y = fmaf(a.y, b.y, c.y); return r;
#endif
}

__global__ __launch_bounds__(NT, 2)
void ssim_main(const float* __restrict__ X, const float* __restrict__ Y,
               const float* __restrict__ Wg, double* __restrict__ acc)
{
    // 9-row LDS ring: Prow[row%9][col] = (x_col, y_col). Phase p writes rows
    // 3p+9..3p+11 (slots {3q,3q+1,3q+2} mod 9), phase p reads rows 3p+8..3p+10
    // (slots {3q+8,3q,3q+1}) -> phase p+1 writes never touch phase p reads,
    // so ONE barrier per phase is race-free.
    __shared__ float2 Prow[9][PW];
    __shared__ float  wsum[4][2];

    const int t  = threadIdx.x;
    const int r0 = blockIdx.x * RROWS;          // multiple of 9
    const int c0 = blockIdx.y * STRIP;
    const size_t ibase = (size_t)blockIdx.z * (size_t)(WID * HEI);

    const bool ldv  = (t < NLD) && (c0 + 2 * t < WID);   // loader role
    const bool ownc = (t < 128);                          // halo chunks not owned

    // 1D gaussian from row 4 of w2d: w2d[4][k] = g4*g[k], row sum = g4
    float g[9];
    {
        float s = 0.f;
        sfor<9>([&](auto K) { constexpr int k = decltype(K)::v;
            g[k] = Wg[36 + k]; s += g[k]; });
        float rs = __builtin_amdgcn_rcpf(s);
        sfor<9>([&](auto K) { constexpr int k = decltype(K)::v; g[k] *= rs; });
    }

    const float C1 = 0.0004f, C2 = 0.0036f;
    float ssim_acc = 0.f, l1_acc = 0.f;

    // register ring of horizontal-conv rows (45 VGPRs), + 3-row pending pipeline
    v2f  r01[9], r23[9];
    float r4[9];
    float2 pbx[3], pby[3];

    const float2* __restrict__ Xp = (const float2*)(X + ibase + c0);
    const float2* __restrict__ Yp = (const float2*)(Y + ibase + c0);

    auto issue = [&](int ro, auto S) {        // load row r0+ro -> pending slot s
        constexpr int s = decltype(S)::v;
        const int row = r0 + ro;
        if (ldv && row < HEI) {
            pbx[s] = Xp[(size_t)row * (WID / 2) + t];
            pby[s] = Yp[(size_t)row * (WID / 2) + t];
        }
    };
    auto store = [&](int ro, auto S, auto LS) {  // pending slot s -> LDS slot ls
        constexpr int s  = decltype(S)::v;
        constexpr int ls = decltype(LS)::v;
        const int row = r0 + ro;
        if (ldv && row < HEI) {
            float4* dst = (float4*)&Prow[ls][2 * t];
            *dst = make_float4(pbx[s].x, pby[s].x, pbx[s].y, pby[s].y);
            if (ownc && ro < RROWS)   // L1 over exclusively-owned rows/cols
                l1_acc += fabsf(pbx[s].x - pby[s].x) + fabsf(pbx[s].y - pby[s].y);
        }
    };
    auto hcomp = [&](auto LS, auto RS) {      // horizontal 9-tap, LDS -> ring
        constexpr int ls = decltype(LS)::v;
        constexpr int rs = decltype(RS)::v;
        v2f s01 = (v2f)0.f, s23 = (v2f)0.f; float s4 = 0.f;
        sfor<9>([&](auto K) { constexpr int k = decltype(K)::v;
            float2 p = Prow[ls][t + k];
            v2f a = { p.x, p.y };
            v2f gk2 = { g[k], g[k] };
            s01 = pkfma(gk2, a, s01);
            s23 = pkfma(gk2, a * a, s23);
            s4  = fmaf(g[k], p.x * p.y, s4);
        });
        r01[rs] = s01; r23[rs] = s23; r4[rs] = s4;
    };

    const bool vA = (c0 + t < OWD);

    auto outrow = [&](int j, auto JM) {       // vertical 9-tap + SSIM for row j
        constexpr int jm = decltype(JM)::v;
        if (r0 + j < OWD) {                   // block-uniform guard
            v2f u01 = (v2f)0.f, u23 = (v2f)0.f; float u4 = 0.f;
            sfor<9>([&](auto K) { constexpr int k = decltype(K)::v;
                constexpr int s = (jm + k) % 9;
                v2f gk2 = { g[k], g[k] };
                u01 = pkfma(gk2, r01[s], u01);
                u23 = pkfma(gk2, r23[s], u23);
                u4  = fmaf(g[k], r4[s], u4);
            });
            float ux = u01.x, uy = u01.y, uxx = u23.x, uyy = u23.y, uxy = u4;
            float uxux = ux * ux, uyuy = uy * uy, uxuy = ux * uy;
            float A1 = 2.f * uxuy + C1;
            float A2 = 2.f * (uxy - uxuy) + C2;
            float B1 = uxux + uyuy + C1;
            float B2 = (uxx - uxux) + (uyy - uyuy) + C2;
            float S  = (A1 * A2) * __builtin_amdgcn_rcpf(B1 * B2);
            ssim_acc += vA ? S : 0.f;
        }
    };

    // ---- prologue: rows 0..8 staged+hcomp'd (row 8's hcomp deferred to steady)
    issue(0, IC<0>{}); issue(1, IC<1>{}); issue(2, IC<2>{});
    store(0, IC<0>{}, IC<0>{}); store(1, IC<1>{}, IC<1>{}); store(2, IC<2>{}, IC<2>{});
    __syncthreads();
    issue(3, IC<0>{}); issue(4, IC<1>{}); issue(5, IC<2>{});
    hcomp(IC<0>{}, IC<0>{}); hcomp(IC<1>{}, IC<1>{}); hcomp(IC<2>{}, IC<2>{});

    store(3, IC<0>{}, IC<3>{}); store(4, IC<1>{}, IC<4>{}); store(5, IC<2>{}, IC<5>{});
    __syncthreads();
    issue(6, IC<0>{}); issue(7, IC<1>{}); issue(8, IC<2>{});
    hcomp(IC<3>{}, IC<3>{}); hcomp(IC<4>{}, IC<4>{}); hcomp(IC<5>{}, IC<5>{});

    store(6, IC<0>{}, IC<6>{}); store(7, IC<1>{}, IC<7>{}); store(8, IC<2>{}, IC<8>{});
    __syncthreads();
    issue(9, IC<0>{}); issue(10, IC<1>{}); issue(11, IC<2>{});
    hcomp(IC<6>{}, IC<6>{}); hcomp(IC<7>{}, IC<7>{});

    // ---- steady: 15 phases of 3 output rows; p = 3P+q; one barrier per phase
#pragma unroll 1
    for (int P = 0; P < 5; ++P) {
        const int jb = 9 * P;
        sfor<3>([&](auto Q) {
            constexpr int q = decltype(Q)::v;
            const int p  = 3 * P + q;
            const int j0 = jb + 3 * q;
            // stage rows 3p+9..3p+11 (loaded last phase)
            store(j0 + 9,  IC<0>{}, IC<(3 * q) % 9>{});
            store(j0 + 10, IC<1>{}, IC<(3 * q + 1) % 9>{});
            store(j0 + 11, IC<2>{}, IC<(3 * q + 2) % 9>{});
            __syncthreads();
            if (p < 14) {   // prefetch rows 3p+12..3p+14 (consumed next phase)
                issue(j0 + 12, IC<0>{}); issue(j0 + 13, IC<1>{}); issue(j0 + 14, IC<2>{});
            }
            hcomp(IC<(3 * q + 8) % 9>{}, IC<(3 * q + 8) % 9>{});
            outrow(j0,     IC<(3 * q) % 9>{});
            hcomp(IC<(3 * q + 9) % 9>{}, IC<(3 * q + 9) % 9>{});
            outrow(j0 + 1, IC<(3 * q + 1) % 9>{});
            hcomp(IC<(3 * q + 10) % 9>{}, IC<(3 * q + 10) % 9>{});
            outrow(j0 + 2, IC<(3 * q + 2) % 9>{});
        });
    }

    // ---- reduction: wave shfl -> LDS -> one double atomic pair per block
#pragma unroll
    for (int off = 32; off > 0; off >>= 1) {
        ssim_acc += __shfl_down(ssim_acc, off);
        l1_acc   += __shfl_down(l1_acc, off);
    }
    const int wid = t >> 6;
    if ((t & 63) == 0) { wsum[wid][0] = ssim_acc; wsum[wid][1] = l1_acc; }
    __syncthreads();
    if (t == 0) {
        double s = 0.0, l = 0.0;
#pragma unroll
        for (int w = 0; w < 4; ++w) { s += (double)wsum[w][0]; l += (double)wsum[w][1]; }
        atomicAdd(acc + 0, s);
        atomicAdd(acc + 1, l);
    }
}

__global__ void ssim_final(const double* __restrict__ acc, float* __restrict__ out)
{
    const double n_ssim = 33032192.0;   // 32*1016*1016
    const double n_l1   = 33554432.0;   // 32*1024*1024
    double ssim_loss = 1.0 - acc[0] / n_ssim;
    double l1        = acc[1] / n_l1;
    out[0] = (float)(0.5 * ssim_loss + 1.0 * l1);
}

extern "C" void kernel_launch(void* const* d_in, const int* in_sizes, int n_in,
                              void* d_out, int out_size, void* d_ws, size_t ws_size,
                              hipStream_t stream)
{
    const float* X  = (const float*)d_in[0];
    const float* Y  = (const float*)d_in[1];
    const float* Wg = (const float*)d_in[2];
    float*  out = (float*)d_out;
    double* acc = (double*)d_ws;

    hipMemsetAsync(acc, 0, 2 * sizeof(double), stream);
    dim3 grid(23, 4, 32);   // rowblocks(ceil(1016/45)) x col-strips x images
    ssim_main<<<grid, NT, 0, stream>>>(X, Y, Wg, acc);
    ssim_final<<<1, 1, 0, stream>>>(acc, out);
}